// Round 5
// baseline (925.978 us; speedup 1.0000x reference)
//
#include <hip/hip_runtime.h>
#include <hip/hip_bf16.h>

#define NN 50000     // nodes
#define NE 600000    // edges
#define NF 11        // raw features
#define DD 128       // hidden dim
#define NB 500       // graphs
#define MA 100       // max atoms per graph
#define NLAY 5       // conv layers
#define NBLK ((NN + 255) / 256)   // 196 scan blocks

// --- zero an int region ----------------------------------------------------
__global__ __launch_bounds__(256) void k_zero(int* __restrict__ p, int n) {
    int i = blockIdx.x * 256 + threadIdx.x;
    if (i < n) p[i] = 0;
}

// --- expansion: x = log(atoms+1) @ W_exp + b_exp ---------------------------
__global__ __launch_bounds__(256) void k_expand(
        const float* __restrict__ atoms,
        const float* __restrict__ W_exp,
        const float* __restrict__ b_exp,
        float* __restrict__ x) {
    int sub  = threadIdx.x >> 7;            // 2 nodes per block
    int node = blockIdx.x * 2 + sub;
    int d    = threadIdx.x & 127;
    __shared__ float la[2][NF];
    if (node < NN && d < NF)
        la[sub][d] = logf(atoms[node * NF + d] + 1.0f);
    __syncthreads();
    if (node >= NN) return;
    float acc = b_exp[d];
#pragma unroll
    for (int f = 0; f < NF; ++f)
        acc = fmaf(la[sub][f], W_exp[f * DD + d], acc);
    x[(size_t)node * DD + d] = acc;
}

// --- degree count ----------------------------------------------------------
__global__ __launch_bounds__(256) void k_count(const int* __restrict__ col,
                                               int* __restrict__ cnt) {
    int e = blockIdx.x * 256 + threadIdx.x;
    if (e < NE) atomicAdd(cnt + col[e], 1);
}

// --- dinv / self_norm ------------------------------------------------------
__global__ __launch_bounds__(256) void k_dinv(const int* __restrict__ cnt,
                                              float* __restrict__ dinv,
                                              float* __restrict__ selfn) {
    int n = blockIdx.x * 256 + threadIdx.x;
    if (n < NN) {
        float r = 1.0f / sqrtf((float)cnt[n] + 2.0f);
        dinv[n]  = r;
        selfn[n] = 2.0f * r * r;
    }
}

// --- hierarchical exclusive scan: cnt -> ptrb ------------------------------
__global__ __launch_bounds__(256) void k_scan1(const int* __restrict__ cnt,
                                               int* __restrict__ ptrb,
                                               int* __restrict__ bsum) {
    __shared__ int s[256];
    int t = threadIdx.x;
    int i = blockIdx.x * 256 + t;
    int v = (i < NN) ? cnt[i] : 0;
    s[t] = v;
    __syncthreads();
    for (int off = 1; off < 256; off <<= 1) {
        int tv = (t >= off) ? s[t - off] : 0;
        __syncthreads();
        s[t] += tv;
        __syncthreads();
    }
    if (i < NN) ptrb[i] = s[t] - v;
    if (t == 255) bsum[blockIdx.x] = s[255];
}

__global__ __launch_bounds__(256) void k_scan2(const int* __restrict__ bsum,
                                               int* __restrict__ boff,
                                               int* __restrict__ ptr_last) {
    __shared__ int s[256];
    int t = threadIdx.x;
    int v = (t < NBLK) ? bsum[t] : 0;
    s[t] = v;
    __syncthreads();
    for (int off = 1; off < 256; off <<= 1) {
        int tv = (t >= off) ? s[t - off] : 0;
        __syncthreads();
        s[t] += tv;
        __syncthreads();
    }
    if (t < NBLK) boff[t] = s[t] - v;
    if (t == 255) *ptr_last = s[255];   // total == NE
}

__global__ __launch_bounds__(256) void k_scan3(int* __restrict__ ptrb,
                                               const int* __restrict__ boff) {
    int i = blockIdx.x * 256 + threadIdx.x;
    if (i < NN) ptrb[i] += boff[blockIdx.x];
}

// --- scatter edges into CSR (sorted by target) -----------------------------
__global__ __launch_bounds__(256) void k_scatter(
        const int* __restrict__ conn, const int* __restrict__ ptrb,
        int* __restrict__ cursor, const float* __restrict__ dinv,
        int* __restrict__ ssrc, float* __restrict__ swt) {
    int e = blockIdx.x * 256 + threadIdx.x;
    if (e < NE) {
        int r = conn[e];
        int c = conn[NE + e];
        int p = ptrb[c] + atomicAdd(cursor + c, 1);
        ssrc[p] = r;
        swt[p]  = dinv[r] * dinv[c];
    }
}

// --- fused layer: x_out = relu( (P x) @ W + b ) ----------------------------
// 16 nodes/block, 256 threads. Phase 1: each wave gathers 4 node-rows of
// y = P x into LDS (float2/lane). Phase 2: LDS-tiled GEMM (W in 2 K-halves).
// LDS: 32KB (W half) + 8KB (y tile) = 40KB -> 4 blocks/CU.
__global__ __launch_bounds__(256) void k_layer(
        const float* __restrict__ x, const int* __restrict__ ptrb,
        const int* __restrict__ ssrc, const float* __restrict__ swt,
        const float* __restrict__ selfn,
        const float* __restrict__ W, const float* __restrict__ bias,
        float* __restrict__ xo) {
    __shared__ float Wl[64 * DD];   // 32 KB
    __shared__ float yt[16 * DD];   // 8 KB
    int tid  = threadIdx.x;
    int wave = tid >> 6, lane = tid & 63;
    int nodebase = blockIdx.x * 16;

    // stage first W half early (overlaps with gather)
    {
        const float4* Wv = (const float4*)W;
        for (int i = tid; i < 64 * DD / 4; i += 256)
            ((float4*)Wl)[i] = Wv[i];
    }

    // phase 1: gather y rows (4 nodes per wave)
    const float2* x2 = (const float2*)x;
    for (int i = 0; i < 4; ++i) {
        int node = nodebase + wave * 4 + i;
        int p0 = ptrb[node], p1 = ptrb[node + 1];
        float sn = selfn[node];
        float2 v = x2[(size_t)node * 64 + lane];
        float a0 = v.x * sn, a1 = v.y * sn;
        for (int p = p0; p < p1; ++p) {
            int   s = ssrc[p];
            float w = swt[p];
            float2 u = x2[(size_t)s * 64 + lane];
            a0 = fmaf(u.x, w, a0);
            a1 = fmaf(u.y, w, a1);
        }
        float2 o; o.x = a0; o.y = a1;
        *(float2*)&yt[(wave * 4 + i) * DD + lane * 2] = o;
    }
    __syncthreads();

    // phase 2: GEMM + bias + relu
    int dg = tid & 31;  int d0 = dg * 4;
    int np = tid >> 5;  int n0 = np * 2, n1 = n0 + 1;
    float a0x = 0, a0y = 0, a0z = 0, a0w = 0;
    float a1x = 0, a1y = 0, a1z = 0, a1w = 0;

#pragma unroll
    for (int half = 0; half < 2; ++half) {
        if (half == 1) {
            __syncthreads();   // everyone done reading Wl half 0
            const float4* Wv = (const float4*)(W + (size_t)64 * DD);
            for (int i = tid; i < 64 * DD / 4; i += 256)
                ((float4*)Wl)[i] = Wv[i];
            __syncthreads();
        }
        int kb = half * 64;
#pragma unroll 4
        for (int k = 0; k < 64; ++k) {
            float4 wv = *(const float4*)&Wl[k * DD + d0];
            float ya = yt[n0 * DD + kb + k];
            float yb = yt[n1 * DD + kb + k];
            a0x = fmaf(wv.x, ya, a0x); a0y = fmaf(wv.y, ya, a0y);
            a0z = fmaf(wv.z, ya, a0z); a0w = fmaf(wv.w, ya, a0w);
            a1x = fmaf(wv.x, yb, a1x); a1y = fmaf(wv.y, yb, a1y);
            a1z = fmaf(wv.z, yb, a1z); a1w = fmaf(wv.w, yb, a1w);
        }
    }
    float4 bv = ((const float4*)bias)[dg];
    float4 o0, o1;
    o0.x = fmaxf(a0x + bv.x, 0.0f); o0.y = fmaxf(a0y + bv.y, 0.0f);
    o0.z = fmaxf(a0z + bv.z, 0.0f); o0.w = fmaxf(a0w + bv.w, 0.0f);
    o1.x = fmaxf(a1x + bv.x, 0.0f); o1.y = fmaxf(a1y + bv.y, 0.0f);
    o1.z = fmaxf(a1z + bv.z, 0.0f); o1.w = fmaxf(a1w + bv.w, 0.0f);
    *(float4*)&xo[(size_t)(nodebase + n0) * DD + d0] = o0;
    *(float4*)&xo[(size_t)(nodebase + n1) * DD + d0] = o1;
}

// --- per-graph counts ------------------------------------------------------
__global__ __launch_bounds__(256) void k_gcount(const int* __restrict__ batch,
                                                int* __restrict__ gcnt) {
    int n = blockIdx.x * 256 + threadIdx.x;
    if (n < NN) atomicAdd(gcnt + batch[n], 1);
}

__global__ __launch_bounds__(512) void k_gscan(const int* __restrict__ gcnt,
                                               int* __restrict__ gptr) {
    __shared__ int s[512];
    int t = threadIdx.x;
    int v = (t < NB) ? gcnt[t] : 0;
    s[t] = v;
    __syncthreads();
    for (int off = 1; off < 512; off <<= 1) {
        int tv = (t >= off) ? s[t - off] : 0;
        __syncthreads();
        s[t] += tv;
        __syncthreads();
    }
    if (t < NB) gptr[t] = s[t] - v;
}

// --- to_dense_batch output: dense f32 [B*MA*DD] then mask f32 [B*MA] -------
__global__ __launch_bounds__(256) void k_output(
        const float* __restrict__ x, const int* __restrict__ batch,
        const int* __restrict__ gptr, float* __restrict__ out) {
    int sub  = threadIdx.x >> 7;
    int node = blockIdx.x * 2 + sub;
    int d    = threadIdx.x & 127;
    if (node >= NN) return;
    int b   = batch[node];
    int pos = node - gptr[b];
    int idx = b * MA + pos;
    out[(size_t)idx * DD + d] = x[(size_t)node * DD + d];
    if (d == 0)
        out[(size_t)NB * MA * DD + idx] = 1.0f;   // mask True -> 1.0f
}

extern "C" void kernel_launch(void* const* d_in, const int* in_sizes, int n_in,
                              void* d_out, int out_size, void* d_ws, size_t ws_size,
                              hipStream_t stream) {
    const float* atoms = (const float*)d_in[0];
    const int*   conn  = (const int*)d_in[1];
    const int*   batch = (const int*)d_in[2];
    const float* W_exp = (const float*)d_in[3];
    const float* b_exp = (const float*)d_in[4];
    const float* Ws    = (const float*)d_in[5];
    const float* bs    = (const float*)d_in[6];
    float* out = (float*)d_out;   // reference output dtype is float32

    char* ws = (char*)d_ws;
    size_t off = 0;
    auto nextbuf = [&](size_t bytes) {
        void* p = ws + off;
        off = (off + bytes + 255) & ~(size_t)255;
        return p;
    };
    float* xbuf  = (float*)nextbuf((size_t)NN * DD * 4);
    float* ybuf  = (float*)nextbuf((size_t)NN * DD * 4);
    int*   izero = (int*)  nextbuf((size_t)(2 * NN + NB) * 4);  // cnt|cursor|gcnt
    int*   cnt    = izero;
    int*   cursor = izero + NN;
    int*   gcnt   = izero + 2 * NN;
    int*   ptrb  = (int*)  nextbuf((size_t)(NN + 1) * 4);
    float* dinv  = (float*)nextbuf((size_t)NN * 4);
    float* selfn = (float*)nextbuf((size_t)NN * 4);
    int*   ssrc  = (int*)  nextbuf((size_t)NE * 4);
    float* swt   = (float*)nextbuf((size_t)NE * 4);
    int*   gptr  = (int*)  nextbuf((size_t)NB * 4);
    int*   bsum  = (int*)  nextbuf((size_t)NBLK * 4);
    int*   boff  = (int*)  nextbuf((size_t)NBLK * 4);
    (void)ws_size; (void)n_in; (void)in_sizes; (void)out_size;

    const int NZ = 2 * NN + NB;
    k_zero   <<<(NZ + 255) / 256,    256, 0, stream>>>(izero, NZ);
    k_expand <<<NN / 2,              256, 0, stream>>>(atoms, W_exp, b_exp, xbuf);
    k_count  <<<(NE + 255) / 256,    256, 0, stream>>>(conn + NE, cnt);
    k_dinv   <<<(NN + 255) / 256,    256, 0, stream>>>(cnt, dinv, selfn);
    k_scan1  <<<NBLK,                256, 0, stream>>>(cnt, ptrb, bsum);
    k_scan2  <<<1,                   256, 0, stream>>>(bsum, boff, ptrb + NN);
    k_scan3  <<<NBLK,                256, 0, stream>>>(ptrb, boff);
    k_scatter<<<(NE + 255) / 256,    256, 0, stream>>>(conn, ptrb, cursor, dinv, ssrc, swt);
    k_gcount <<<(NN + 255) / 256,    256, 0, stream>>>(batch, gcnt);
    k_gscan  <<<1,                   512, 0, stream>>>(gcnt, gptr);

    float* xa = xbuf;
    float* xb = ybuf;
    for (int l = 0; l < NLAY; ++l) {
        k_layer<<<NN / 16, 256, 0, stream>>>(xa, ptrb, ssrc, swt, selfn,
                                             Ws + (size_t)l * DD * DD,
                                             bs + (size_t)l * DD, xb);
        float* t = xa; xa = xb; xb = t;
    }
    k_output<<<NN / 2, 256, 0, stream>>>(xa, batch, gptr, out);
}

// Round 6
// 724.276 us; speedup vs baseline: 1.2785x; 1.2785x over previous
//
#include <hip/hip_runtime.h>
#include <hip/hip_bf16.h>

#define NN 50000     // nodes
#define NE 600000    // edges
#define NF 11        // raw features
#define DD 128       // hidden dim
#define NB 500       // graphs
#define MA 100       // max atoms per graph
#define NLAY 5       // conv layers
#define NBLK ((NN + 255) / 256)   // 196 scan blocks

static __device__ __forceinline__ float bflo(unsigned u) {
    return __uint_as_float(u << 16);
}
static __device__ __forceinline__ float bfhi(unsigned u) {
    return __uint_as_float(u & 0xffff0000u);
}

// --- zero an int region ----------------------------------------------------
__global__ __launch_bounds__(256) void k_zero(int* __restrict__ p, int n) {
    int i = blockIdx.x * 256 + threadIdx.x;
    if (i < n) p[i] = 0;
}

// --- expansion: xb = bf16( log(atoms+1) @ W_exp + b_exp ) ------------------
__global__ __launch_bounds__(256) void k_expand(
        const float* __restrict__ atoms,
        const float* __restrict__ W_exp,
        const float* __restrict__ b_exp,
        __hip_bfloat16* __restrict__ xb) {
    int sub  = threadIdx.x >> 7;            // 2 nodes per block
    int node = blockIdx.x * 2 + sub;
    int d    = threadIdx.x & 127;
    __shared__ float la[2][NF];
    if (node < NN && d < NF)
        la[sub][d] = logf(atoms[node * NF + d] + 1.0f);
    __syncthreads();
    if (node >= NN) return;
    float acc = b_exp[d];
#pragma unroll
    for (int f = 0; f < NF; ++f)
        acc = fmaf(la[sub][f], W_exp[f * DD + d], acc);
    xb[(size_t)node * DD + d] = __float2bfloat16(acc);
}

// --- degree count ----------------------------------------------------------
__global__ __launch_bounds__(256) void k_count(const int* __restrict__ col,
                                               int* __restrict__ cnt) {
    int e = blockIdx.x * 256 + threadIdx.x;
    if (e < NE) atomicAdd(cnt + col[e], 1);
}

// --- dinv / self_norm ------------------------------------------------------
__global__ __launch_bounds__(256) void k_dinv(const int* __restrict__ cnt,
                                              float* __restrict__ dinv,
                                              float* __restrict__ selfn) {
    int n = blockIdx.x * 256 + threadIdx.x;
    if (n < NN) {
        float r = 1.0f / sqrtf((float)cnt[n] + 2.0f);
        dinv[n]  = r;
        selfn[n] = 2.0f * r * r;
    }
}

// --- hierarchical exclusive scan: cnt -> ptrb ------------------------------
__global__ __launch_bounds__(256) void k_scan1(const int* __restrict__ cnt,
                                               int* __restrict__ ptrb,
                                               int* __restrict__ bsum) {
    __shared__ int s[256];
    int t = threadIdx.x;
    int i = blockIdx.x * 256 + t;
    int v = (i < NN) ? cnt[i] : 0;
    s[t] = v;
    __syncthreads();
    for (int off = 1; off < 256; off <<= 1) {
        int tv = (t >= off) ? s[t - off] : 0;
        __syncthreads();
        s[t] += tv;
        __syncthreads();
    }
    if (i < NN) ptrb[i] = s[t] - v;
    if (t == 255) bsum[blockIdx.x] = s[255];
}

__global__ __launch_bounds__(256) void k_scan2(const int* __restrict__ bsum,
                                               int* __restrict__ boff,
                                               int* __restrict__ ptr_last) {
    __shared__ int s[256];
    int t = threadIdx.x;
    int v = (t < NBLK) ? bsum[t] : 0;
    s[t] = v;
    __syncthreads();
    for (int off = 1; off < 256; off <<= 1) {
        int tv = (t >= off) ? s[t - off] : 0;
        __syncthreads();
        s[t] += tv;
        __syncthreads();
    }
    if (t < NBLK) boff[t] = s[t] - v;
    if (t == 255) *ptr_last = s[255];   // total == NE
}

__global__ __launch_bounds__(256) void k_scan3(int* __restrict__ ptrb,
                                               const int* __restrict__ boff) {
    int i = blockIdx.x * 256 + threadIdx.x;
    if (i < NN) ptrb[i] += boff[blockIdx.x];
}

// --- scatter edges into CSR (sorted by target) -----------------------------
__global__ __launch_bounds__(256) void k_scatter(
        const int* __restrict__ conn, const int* __restrict__ ptrb,
        int* __restrict__ cursor, const float* __restrict__ dinv,
        int* __restrict__ ssrc, float* __restrict__ swt) {
    int e = blockIdx.x * 256 + threadIdx.x;
    if (e < NE) {
        int r = conn[e];
        int c = conn[NE + e];
        int p = ptrb[c] + atomicAdd(cursor + c, 1);
        ssrc[p] = r;
        swt[p]  = dinv[r] * dinv[c];
    }
}

// --- per-graph counts / scan -----------------------------------------------
__global__ __launch_bounds__(256) void k_gcount(const int* __restrict__ batch,
                                                int* __restrict__ gcnt) {
    int n = blockIdx.x * 256 + threadIdx.x;
    if (n < NN) atomicAdd(gcnt + batch[n], 1);
}

__global__ __launch_bounds__(512) void k_gscan(const int* __restrict__ gcnt,
                                               int* __restrict__ gptr) {
    __shared__ int s[512];
    int t = threadIdx.x;
    int v = (t < NB) ? gcnt[t] : 0;
    s[t] = v;
    __syncthreads();
    for (int off = 1; off < 512; off <<= 1) {
        int tv = (t >= off) ? s[t - off] : 0;
        __syncthreads();
        s[t] += tv;
        __syncthreads();
    }
    if (t < NB) gptr[t] = s[t] - v;
}

// --- fused layer: relu( (P xb) @ W + b ) -----------------------------------
// 16 nodes/block, 256 threads, LDS = y tile only (8 KB) -> 8 blocks/CU.
// Phase 1: each wave gathers 4 node-rows (bf16 x, f32 accum) into LDS.
// Phase 2: per-thread 2 nodes x 4 cols; W read straight from global (L1/L2
// broadcast, 64 KB); yt read as float4 LDS broadcasts.
// last==0: write bf16 x_out. last==1: write f32 dense out + mask.
__global__ __launch_bounds__(256) void k_layer(
        const __hip_bfloat16* __restrict__ xb, const int* __restrict__ ptrb,
        const int* __restrict__ ssrc, const float* __restrict__ swt,
        const float* __restrict__ selfn,
        const float* __restrict__ W, const float* __restrict__ bias,
        __hip_bfloat16* __restrict__ xob,
        int last, const int* __restrict__ batch, const int* __restrict__ gptr,
        float* __restrict__ out) {
    __shared__ float yt[16 * DD];   // 8 KB
    int tid  = threadIdx.x;
    int wave = tid >> 6, lane = tid & 63;
    int nodebase = blockIdx.x * 16;

    // phase 1: gather y rows (4 nodes per wave), bf16 source, f32 accum
    const unsigned* xq = (const unsigned*)xb;   // 2 bf16 per word
    for (int i = 0; i < 4; ++i) {
        int node = nodebase + wave * 4 + i;
        int p0 = ptrb[node], p1 = ptrb[node + 1];
        float sn = selfn[node];
        unsigned u = xq[(size_t)node * 64 + lane];
        float a0 = bflo(u) * sn, a1 = bfhi(u) * sn;
        for (int p = p0; p < p1; ++p) {
            int   s = ssrc[p];
            float w = swt[p];
            unsigned v = xq[(size_t)s * 64 + lane];
            a0 = fmaf(bflo(v), w, a0);
            a1 = fmaf(bfhi(v), w, a1);
        }
        float2 o; o.x = a0; o.y = a1;
        *(float2*)&yt[(wave * 4 + i) * DD + lane * 2] = o;
    }
    __syncthreads();

    // phase 2: GEMM + bias + relu
    int dg = tid & 31;  int d0 = dg * 4;
    int np = tid >> 5;  int n0 = np * 2, n1 = n0 + 1;
    const float4* W4  = (const float4*)W;
    const float4* y40 = (const float4*)&yt[n0 * DD];
    const float4* y41 = (const float4*)&yt[n1 * DD];
    float a0x = 0, a0y = 0, a0z = 0, a0w = 0;
    float a1x = 0, a1y = 0, a1z = 0, a1w = 0;
#pragma unroll 4
    for (int kk = 0; kk < 32; ++kk) {
        float4 ya = y40[kk];
        float4 yb = y41[kk];
        float4 w0 = W4[(kk * 4 + 0) * 32 + dg];
        float4 w1 = W4[(kk * 4 + 1) * 32 + dg];
        float4 w2 = W4[(kk * 4 + 2) * 32 + dg];
        float4 w3 = W4[(kk * 4 + 3) * 32 + dg];
        a0x = fmaf(w0.x, ya.x, a0x); a0y = fmaf(w0.y, ya.x, a0y);
        a0z = fmaf(w0.z, ya.x, a0z); a0w = fmaf(w0.w, ya.x, a0w);
        a1x = fmaf(w0.x, yb.x, a1x); a1y = fmaf(w0.y, yb.x, a1y);
        a1z = fmaf(w0.z, yb.x, a1z); a1w = fmaf(w0.w, yb.x, a1w);
        a0x = fmaf(w1.x, ya.y, a0x); a0y = fmaf(w1.y, ya.y, a0y);
        a0z = fmaf(w1.z, ya.y, a0z); a0w = fmaf(w1.w, ya.y, a0w);
        a1x = fmaf(w1.x, yb.y, a1x); a1y = fmaf(w1.y, yb.y, a1y);
        a1z = fmaf(w1.z, yb.y, a1z); a1w = fmaf(w1.w, yb.y, a1w);
        a0x = fmaf(w2.x, ya.z, a0x); a0y = fmaf(w2.y, ya.z, a0y);
        a0z = fmaf(w2.z, ya.z, a0z); a0w = fmaf(w2.w, ya.z, a0w);
        a1x = fmaf(w2.x, yb.z, a1x); a1y = fmaf(w2.y, yb.z, a1y);
        a1z = fmaf(w2.z, yb.z, a1z); a1w = fmaf(w2.w, yb.z, a1w);
        a0x = fmaf(w3.x, ya.w, a0x); a0y = fmaf(w3.y, ya.w, a0y);
        a0z = fmaf(w3.z, ya.w, a0z); a0w = fmaf(w3.w, ya.w, a0w);
        a1x = fmaf(w3.x, yb.w, a1x); a1y = fmaf(w3.y, yb.w, a1y);
        a1z = fmaf(w3.z, yb.w, a1z); a1w = fmaf(w3.w, yb.w, a1w);
    }
    float4 bv = ((const float4*)bias)[dg];
    float o0x = fmaxf(a0x + bv.x, 0.0f), o0y = fmaxf(a0y + bv.y, 0.0f);
    float o0z = fmaxf(a0z + bv.z, 0.0f), o0w = fmaxf(a0w + bv.w, 0.0f);
    float o1x = fmaxf(a1x + bv.x, 0.0f), o1y = fmaxf(a1y + bv.y, 0.0f);
    float o1z = fmaxf(a1z + bv.z, 0.0f), o1w = fmaxf(a1w + bv.w, 0.0f);

    int nodeA = nodebase + n0, nodeB = nodebase + n1;
    if (!last) {
        ushort4 pa, pb;
        pa.x = __bfloat16_as_ushort(__float2bfloat16(o0x));
        pa.y = __bfloat16_as_ushort(__float2bfloat16(o0y));
        pa.z = __bfloat16_as_ushort(__float2bfloat16(o0z));
        pa.w = __bfloat16_as_ushort(__float2bfloat16(o0w));
        pb.x = __bfloat16_as_ushort(__float2bfloat16(o1x));
        pb.y = __bfloat16_as_ushort(__float2bfloat16(o1y));
        pb.z = __bfloat16_as_ushort(__float2bfloat16(o1z));
        pb.w = __bfloat16_as_ushort(__float2bfloat16(o1w));
        *(ushort4*)((unsigned short*)xob + (size_t)nodeA * DD + d0) = pa;
        *(ushort4*)((unsigned short*)xob + (size_t)nodeB * DD + d0) = pb;
    } else {
        int ba = batch[nodeA], bb = batch[nodeB];
        int ia = ba * MA + (nodeA - gptr[ba]);
        int ib = bb * MA + (nodeB - gptr[bb]);
        float4 oa; oa.x = o0x; oa.y = o0y; oa.z = o0z; oa.w = o0w;
        float4 ob; ob.x = o1x; ob.y = o1y; ob.z = o1z; ob.w = o1w;
        *(float4*)&out[(size_t)ia * DD + d0] = oa;
        *(float4*)&out[(size_t)ib * DD + d0] = ob;
        if (dg == 0) {
            out[(size_t)NB * MA * DD + ia] = 1.0f;
            out[(size_t)NB * MA * DD + ib] = 1.0f;
        }
    }
}

extern "C" void kernel_launch(void* const* d_in, const int* in_sizes, int n_in,
                              void* d_out, int out_size, void* d_ws, size_t ws_size,
                              hipStream_t stream) {
    const float* atoms = (const float*)d_in[0];
    const int*   conn  = (const int*)d_in[1];
    const int*   batch = (const int*)d_in[2];
    const float* W_exp = (const float*)d_in[3];
    const float* b_exp = (const float*)d_in[4];
    const float* Ws    = (const float*)d_in[5];
    const float* bs    = (const float*)d_in[6];
    float* out = (float*)d_out;   // reference output dtype is float32

    char* ws = (char*)d_ws;
    size_t off = 0;
    auto nextbuf = [&](size_t bytes) {
        void* p = ws + off;
        off = (off + bytes + 255) & ~(size_t)255;
        return p;
    };
    __hip_bfloat16* xb0 = (__hip_bfloat16*)nextbuf((size_t)NN * DD * 2);
    __hip_bfloat16* xb1 = (__hip_bfloat16*)nextbuf((size_t)NN * DD * 2);
    int*   izero = (int*)  nextbuf((size_t)(2 * NN + NB) * 4);  // cnt|cursor|gcnt
    int*   cnt    = izero;
    int*   cursor = izero + NN;
    int*   gcnt   = izero + 2 * NN;
    int*   ptrb  = (int*)  nextbuf((size_t)(NN + 1) * 4);
    float* dinv  = (float*)nextbuf((size_t)NN * 4);
    float* selfn = (float*)nextbuf((size_t)NN * 4);
    int*   ssrc  = (int*)  nextbuf((size_t)NE * 4);
    float* swt   = (float*)nextbuf((size_t)NE * 4);
    int*   gptr  = (int*)  nextbuf((size_t)NB * 4);
    int*   bsum  = (int*)  nextbuf((size_t)NBLK * 4);
    int*   boff  = (int*)  nextbuf((size_t)NBLK * 4);
    (void)ws_size; (void)n_in; (void)in_sizes; (void)out_size;

    const int NZ = 2 * NN + NB;
    k_zero   <<<(NZ + 255) / 256,    256, 0, stream>>>(izero, NZ);
    k_expand <<<NN / 2,              256, 0, stream>>>(atoms, W_exp, b_exp, xb0);
    k_count  <<<(NE + 255) / 256,    256, 0, stream>>>(conn + NE, cnt);
    k_dinv   <<<(NN + 255) / 256,    256, 0, stream>>>(cnt, dinv, selfn);
    k_scan1  <<<NBLK,                256, 0, stream>>>(cnt, ptrb, bsum);
    k_scan2  <<<1,                   256, 0, stream>>>(bsum, boff, ptrb + NN);
    k_scan3  <<<NBLK,                256, 0, stream>>>(ptrb, boff);
    k_scatter<<<(NE + 255) / 256,    256, 0, stream>>>(conn, ptrb, cursor, dinv, ssrc, swt);
    k_gcount <<<(NN + 255) / 256,    256, 0, stream>>>(batch, gcnt);
    k_gscan  <<<1,                   512, 0, stream>>>(gcnt, gptr);

    __hip_bfloat16* xa = xb0;
    __hip_bfloat16* xb = xb1;
    for (int l = 0; l < NLAY; ++l) {
        int last = (l == NLAY - 1);
        k_layer<<<NN / 16, 256, 0, stream>>>(xa, ptrb, ssrc, swt, selfn,
                                             Ws + (size_t)l * DD * DD,
                                             bs + (size_t)l * DD,
                                             xb, last, batch, gptr, out);
        __hip_bfloat16* t = xa; xa = xb; xb = t;
    }
}